// Round 5
// baseline (446.059 us; speedup 1.0000x reference)
//
#include <hip/hip_runtime.h>
#include <hip/hip_bf16.h>
#include <math.h>

// Problem constants
#define BB 8
#define TT 1024
#define CC 768
#define HH 12
#define HD 64
#define MM (BB*TT)           // 8192 rows
#define NELT (MM*CC)         // 6291456 elements per tensor
#define WELT (CC*CC)         // 589824 elements per weight

typedef short bf16x8 __attribute__((ext_vector_type(8)));   // 8 bf16 = 4 VGPR
typedef float f32x4  __attribute__((ext_vector_type(4)));   // MFMA accum

__device__ __forceinline__ short f2bf(float f) {
    union { float f; unsigned u; } a; a.f = f;
    unsigned r = a.u + 0x7fffu + ((a.u >> 16) & 1u);        // RNE
    return (short)(r >> 16);
}
__device__ __forceinline__ float bf2f(short s) {
    union { unsigned u; float f; } a; a.u = ((unsigned)(unsigned short)s) << 16;
    return a.f;
}

// ---------------------------------------------------------------------------
// Convert f32 -> bf16: x (NELT) and Wq/Wk/Wv (3*WELT packed) in one pass.
// ---------------------------------------------------------------------------
#define N4X (NELT/4)         // 1572864
#define N4W (WELT/4)         // 147456
__global__ __launch_bounds__(256)
void convert_all(const float* __restrict__ x,
                 const float* __restrict__ Wq, const float* __restrict__ Wk,
                 const float* __restrict__ Wv,
                 short* __restrict__ xb, short* __restrict__ wb)
{
    const int i = blockIdx.x * 256 + threadIdx.x;   // float4 index
    const float* src; short* dst; int off;
    if (i < N4X) { src = x; dst = xb; off = i; }
    else {
        const int j = i - N4X;
        const int w = j / N4W;  off = j - w * N4W;
        src = (w == 0) ? Wq : (w == 1) ? Wk : Wv;
        dst = wb + w * WELT;
    }
    const float4 v = ((const float4*)src)[off];
    short4 h;
    h.x = f2bf(v.x); h.y = f2bf(v.y); h.z = f2bf(v.z); h.w = f2bf(v.w);
    ((short4*)dst)[off] = h;
}

__global__ __launch_bounds__(256)
void convert_wo(const float* __restrict__ Wo, short* __restrict__ wob)
{
    const int i = blockIdx.x * 256 + threadIdx.x;   // float4 index, N4W total
    const float4 v = ((const float4*)Wo)[i];
    short4 h;
    h.x = f2bf(v.x); h.y = f2bf(v.y); h.z = f2bf(v.z); h.w = f2bf(v.w);
    ((short4*)wob)[i] = h;
}

// ---------------------------------------------------------------------------
// bf16 MFMA GEMM core: C[128,128] tile of A[M,768] @ W[N,768]^T, both bf16.
// 256 thr = 4 waves (2x2), wave = 64x64 out = 4x4 16x16 frags. BK=32.
// LDS [128][32] linear rows (64B); 16B-chunk col XOR-swizzled by (row>>1)&3
// on BOTH write and read -> 2-way (free) banking for ds_write_b128 and
// ds_read_b128. Next K-step's 4 int4 are prefetched into regs before the
// compute phase (issue overlaps MFMA, T14-lite).
// ---------------------------------------------------------------------------
__device__ __forceinline__ void gemm_core_bf(const short* __restrict__ A,
                                             const short* __restrict__ W,
                                             int row0, int col0,
                                             f32x4 acc[4][4])
{
    __shared__ short As[128][32];
    __shared__ short Bs[128][32];
    const int tid  = threadIdx.x;
    const int lane = tid & 63;
    const int wid  = tid >> 6;
    const int wr   = (wid >> 1) * 64;
    const int wc   = (wid & 1) * 64;
    const int fr   = lane & 15;
    const int fg   = lane >> 4;

    // staging decode (2 chunks per operand per thread)
    int rA[2], cA[2];
#pragma unroll
    for (int i = 0; i < 2; ++i) { const int p = i * 256 + tid; rA[i] = p >> 2; cA[i] = p & 3; }

    int4 ar[2], br[2];
#pragma unroll
    for (int i = 0; i < 2; ++i) {
        ar[i] = *(const int4*)&A[(size_t)(row0 + rA[i]) * 768 + cA[i] * 8];
        br[i] = *(const int4*)&W[(size_t)(col0 + rA[i]) * 768 + cA[i] * 8];
    }

    for (int k0 = 0; k0 < 768; k0 += 32) {
        __syncthreads();
#pragma unroll
        for (int i = 0; i < 2; ++i) {
            const int sw = (rA[i] >> 1) & 3;
            *(int4*)&As[rA[i]][(cA[i] ^ sw) * 8] = ar[i];
            *(int4*)&Bs[rA[i]][(cA[i] ^ sw) * 8] = br[i];
        }
        if (k0 + 32 < 768) {
#pragma unroll
            for (int i = 0; i < 2; ++i) {
                ar[i] = *(const int4*)&A[(size_t)(row0 + rA[i]) * 768 + k0 + 32 + cA[i] * 8];
                br[i] = *(const int4*)&W[(size_t)(col0 + rA[i]) * 768 + k0 + 32 + cA[i] * 8];
            }
        }
        __syncthreads();

        bf16x8 a[4], b[4];
#pragma unroll
        for (int m = 0; m < 4; ++m) {
            const int ra = wr + m * 16 + fr;
            a[m] = *(const bf16x8*)&As[ra][(fg ^ ((ra >> 1) & 3)) * 8];
        }
#pragma unroll
        for (int n = 0; n < 4; ++n) {
            const int rb = wc + n * 16 + fr;
            b[n] = *(const bf16x8*)&Bs[rb][(fg ^ ((rb >> 1) & 3)) * 8];
        }
#pragma unroll
        for (int m = 0; m < 4; ++m)
#pragma unroll
            for (int n = 0; n < 4; ++n)
                acc[m][n] = __builtin_amdgcn_mfma_f32_16x16x32_bf16(a[m], b[n], acc[m][n], 0, 0, 0);
    }
}

// QKV projection: z=0 -> q bf16 (ws), z=1 -> k f32 (d_out), z=2 -> v f32+bf16.
__global__ __launch_bounds__(256)
void gemm_qkv(const short* __restrict__ xb, const short* __restrict__ wb,
              short* __restrict__ qb, float* __restrict__ kf,
              float* __restrict__ vf, short* __restrict__ vb)
{
    const int z = blockIdx.z;
    const short* W = wb + (size_t)z * WELT;
    const int row0 = blockIdx.x * 128, col0 = blockIdx.y * 128;

    f32x4 acc[4][4];
#pragma unroll
    for (int m = 0; m < 4; ++m)
#pragma unroll
        for (int n = 0; n < 4; ++n) acc[m][n] = (f32x4){0.f, 0.f, 0.f, 0.f};

    gemm_core_bf(xb, W, row0, col0, acc);

    const int lane = threadIdx.x & 63, wid = threadIdx.x >> 6;
    const int fr = lane & 15, fg = lane >> 4;
#pragma unroll
    for (int m = 0; m < 4; ++m) {
#pragma unroll
        for (int j = 0; j < 4; ++j) {
            const int row = row0 + (wid >> 1) * 64 + m * 16 + fg * 4 + j;
            const int b = row >> 10, t = row & 1023;
#pragma unroll
            for (int n = 0; n < 4; ++n) {
                const int col = col0 + (wid & 1) * 64 + n * 16 + fr;
                const int h = col >> 6, hd = col & 63;
                const int idx = (((b * HH + h) << 10) | t) * HD + hd;
                const float val = acc[m][n][j];
                if (z == 0)      qb[idx] = f2bf(val);
                else if (z == 1) kf[idx] = val;
                else             { vf[idx] = val; vb[idx] = f2bf(val); }
            }
        }
    }
}

// Output projection: y = y_att(bf16) @ Wo^T(bf16), f32 out.
__global__ __launch_bounds__(256)
void gemm_out(const short* __restrict__ yab, const short* __restrict__ wob,
              float* __restrict__ y)
{
    const int row0 = blockIdx.x * 128, col0 = blockIdx.y * 128;
    f32x4 acc[4][4];
#pragma unroll
    for (int m = 0; m < 4; ++m)
#pragma unroll
        for (int n = 0; n < 4; ++n) acc[m][n] = (f32x4){0.f, 0.f, 0.f, 0.f};

    gemm_core_bf(yab, wob, row0, col0, acc);

    const int lane = threadIdx.x & 63, wid = threadIdx.x >> 6;
    const int fr = lane & 15, fg = lane >> 4;
#pragma unroll
    for (int m = 0; m < 4; ++m)
#pragma unroll
        for (int j = 0; j < 4; ++j) {
            const int row = row0 + (wid >> 1) * 64 + m * 16 + fg * 4 + j;
#pragma unroll
            for (int n = 0; n < 4; ++n) {
                const int col = col0 + (wid & 1) * 64 + n * 16 + fr;
                y[(size_t)row * CC + col] = acc[m][n][j];
            }
        }
}

// ---------------------------------------------------------------------------
// RoPE + QK-RMSNorm. Wave per (b,h,t) row. q bf16 in-place (fold 1/8 scale);
// k f32 in-place (output) + bf16 copy for attention.
// ---------------------------------------------------------------------------
__global__ __launch_bounds__(256)
void rope_qknorm(short* __restrict__ qb, float* __restrict__ kf,
                 short* __restrict__ kb)
{
    const int row  = blockIdx.x * 4 + (threadIdx.x >> 6);
    const int lane = threadIdx.x & 63;
    const int t    = row & (TT - 1);

    float qv = bf2f(qb[row * HD + lane]);
    float kv = kf[row * HD + lane];

    const int d = lane & 31;
    const float fr = (float)t * powf(10000.f, -(float)d * (1.f / 32.f));
    const float c = cosf(fr), s = sinf(fr);

    const float qp = __shfl_xor(qv, 32);
    const float kp = __shfl_xor(kv, 32);

    float qo, ko;
    if (lane < 32) { qo = qv * c - qp * s;  ko = kv * c - kp * s; }
    else           { qo = qp * s + qv * c;  ko = kp * s + kv * c; }

    float qs = qo * qo, ks = ko * ko;
#pragma unroll
    for (int m = 1; m < 64; m <<= 1) {
        qs += __shfl_xor(qs, m);
        ks += __shfl_xor(ks, m);
    }
    qo *= rsqrtf(qs * (1.f / 64.f) + 1e-6f);
    ko *= rsqrtf(ks * (1.f / 64.f) + 1e-6f);

    qb[row * HD + lane] = f2bf(qo * 0.125f);   // fold 1/sqrt(Hd)
    kf[row * HD + lane] = ko;
    kb[row * HD + lane] = f2bf(ko);
}

// ---------------------------------------------------------------------------
// MFMA flash attention, KVBLK=64. Block = 4 waves, one (b,h), 64 Q rows.
// Per 64-key tile: stage K[64][68] + V^T[64][68] (reg-prefetched for kt+1
// between the barriers, T14), QK^T = 8 MFMA (4 n-slices x 2 k-slices),
// wave-parallel online softmax (1 pass per 64 keys), P -> per-wave LDS
// [16][76] (bank-clean strides), PV = 8 MFMA. No mid-loop barrier: Ps is
// per-wave, Vt was staged before the tile barrier.
// ---------------------------------------------------------------------------
__global__ __launch_bounds__(256)
void attn_mfma(const short* __restrict__ qb, const short* __restrict__ kb,
               const short* __restrict__ vb, short* __restrict__ yab)
{
    __shared__ short Ks[64][68];     // [key][hd]   136B rows -> 2-way free
    __shared__ short Vt[64][68];     // [hd][key]
    __shared__ short Ps[4][16][76];  // per wave [qrow][key] 152B rows

    const int qt   = 15 - blockIdx.x;      // big tiles first
    const int bh   = blockIdx.y;           // 0..95
    const int tid  = threadIdx.x;
    const int lane = tid & 63, wid = tid >> 6;
    const int fr   = lane & 15, fg = lane >> 4;
    const int q0   = qt * 64 + wid * 16;

    const short* qbase = qb + (size_t)(bh << 10) * HD;
    const short* kbase = kb + (size_t)(bh << 10) * HD;
    const short* vbase = vb + (size_t)(bh << 10) * HD;

    // Q fragments (rows q0+fr), pre-scaled by 1/8
    bf16x8 aq[2];
#pragma unroll
    for (int ks = 0; ks < 2; ++ks)
        aq[ks] = *(const bf16x8*)&qbase[(q0 + fr) * HD + ks * 32 + fg * 8];

    f32x4 acc[4];
#pragma unroll
    for (int n = 0; n < 4; ++n) acc[n] = (f32x4){0.f, 0.f, 0.f, 0.f};
    float mrow[4] = {-1e30f, -1e30f, -1e30f, -1e30f};
    float lrow[4] = {0.f, 0.f, 0.f, 0.f};

    // staging decode: 512 16B chunks per tensor, 2 per thread
    int kk_[2], kc_[2], vk_[2], vh_[2];
#pragma unroll
    for (int i = 0; i < 2; ++i) {
        const int p = i * 256 + tid;
        kk_[i] = p >> 3;  kc_[i] = (p & 7) * 8;     // K: key row, hd offset
        vk_[i] = p & 63;  vh_[i] = (p >> 6) * 8;    // V: key, hd block
    }

    int4 kr[2], vr[2];
#pragma unroll
    for (int i = 0; i < 2; ++i) {
        kr[i] = *(const int4*)&kbase[(size_t)kk_[i] * HD + kc_[i]];
        vr[i] = *(const int4*)&vbase[(size_t)vk_[i] * HD + vh_[i]];
    }

    const int ktend = qt + 1;
    for (int kt = 0; kt < ktend; ++kt) {
        __syncthreads();                       // prev tile's readers done
#pragma unroll
        for (int i = 0; i < 2; ++i) {
            *(int4*)&Ks[kk_[i]][kc_[i]] = kr[i];
            const short* vp = (const short*)&vr[i];
#pragma unroll
            for (int j = 0; j < 8; ++j) Vt[vh_[i] + j][vk_[i]] = vp[j];
        }
        if (kt + 1 < ktend) {                  // prefetch next tile (overlaps compute)
#pragma unroll
            for (int i = 0; i < 2; ++i) {
                kr[i] = *(const int4*)&kbase[(size_t)((kt + 1) * 64 + kk_[i]) * HD + kc_[i]];
                vr[i] = *(const int4*)&vbase[(size_t)((kt + 1) * 64 + vk_[i]) * HD + vh_[i]];
            }
        }
        __syncthreads();                       // tile staged

        // S = Q K^T : rows = q (fg*4+j), cols = key (ns*16+fr)
        f32x4 s[4];
#pragma unroll
        for (int ns = 0; ns < 4; ++ns) {
            const bf16x8 bk0 = *(const bf16x8*)&Ks[ns * 16 + fr][fg * 8];
            const bf16x8 bk1 = *(const bf16x8*)&Ks[ns * 16 + fr][32 + fg * 8];
            f32x4 z = (f32x4){0.f, 0.f, 0.f, 0.f};
            z = __builtin_amdgcn_mfma_f32_16x16x32_bf16(aq[0], bk0, z, 0, 0, 0);
            z = __builtin_amdgcn_mfma_f32_16x16x32_bf16(aq[1], bk1, z, 0, 0, 0);
            s[ns] = z;
        }

        const bool diag = (kt == qt);          // only the diagonal tile masks
#pragma unroll
        for (int j = 0; j < 4; ++j) {
            const int q = q0 + fg * 4 + j;
            float sv[4];
#pragma unroll
            for (int ns = 0; ns < 4; ++ns) {
                const int kc = kt * 64 + ns * 16 + fr;
                sv[ns] = (!diag || kc <= q) ? s[ns][j] : -1e30f;
            }
            float cm = fmaxf(fmaxf(sv[0], sv[1]), fmaxf(sv[2], sv[3]));
            cm = fmaxf(cm, __shfl_xor(cm, 1));
            cm = fmaxf(cm, __shfl_xor(cm, 2));
            cm = fmaxf(cm, __shfl_xor(cm, 4));
            cm = fmaxf(cm, __shfl_xor(cm, 8));
            const float mnew = fmaxf(mrow[j], cm);
            const float f = __expf(mrow[j] - mnew);
            float rs = 0.f;
#pragma unroll
            for (int ns = 0; ns < 4; ++ns) {
                const float p = __expf(sv[ns] - mnew);
                rs += p;
                Ps[wid][fg * 4 + j][ns * 16 + fr] = f2bf(p);
            }
            rs += __shfl_xor(rs, 1);
            rs += __shfl_xor(rs, 2);
            rs += __shfl_xor(rs, 4);
            rs += __shfl_xor(rs, 8);
            lrow[j] = lrow[j] * f + rs;
            mrow[j] = mnew;
            acc[0][j] *= f; acc[1][j] *= f; acc[2][j] *= f; acc[3][j] *= f;
        }

        // O += P V  (Ps per-wave: in-wave lgkmcnt ordering, no barrier needed)
#pragma unroll
        for (int ks = 0; ks < 2; ++ks) {
            const bf16x8 pa = *(const bf16x8*)&Ps[wid][fr][ks * 32 + fg * 8];
#pragma unroll
            for (int n = 0; n < 4; ++n) {
                const bf16x8 vfr = *(const bf16x8*)&Vt[n * 16 + fr][ks * 32 + fg * 8];
                acc[n] = __builtin_amdgcn_mfma_f32_16x16x32_bf16(pa, vfr, acc[n], 0, 0, 0);
            }
        }
    }

    // epilogue: y_att (B,T,C) bf16
    const int b = bh / HH, h = bh % HH;
#pragma unroll
    for (int j = 0; j < 4; ++j) {
        const int q = q0 + fg * 4 + j;
        const float inv = 1.f / lrow[j];
#pragma unroll
        for (int n = 0; n < 4; ++n)
            yab[(size_t)(b * TT + q) * CC + h * HD + n * 16 + fr] =
                f2bf(acc[n][j] * inv);
    }
}

// ---------------------------------------------------------------------------
// Workspace aliasing (total = 4*NELT shorts = 50.3MB, proven size):
//   S0: xb (convert..gemm_qkv)            -> yab (attn..gemm_out)
//   S1: Wq/Wk/Wv bf16 (convert..gemm_qkv) -> kb (rope..attn)
//   S2: qb (gemm_qkv..attn)               -> wob (convert_wo..gemm_out)
//   S3: vb (gemm_qkv..attn)
// ---------------------------------------------------------------------------
extern "C" void kernel_launch(void* const* d_in, const int* in_sizes, int n_in,
                              void* d_out, int out_size, void* d_ws, size_t ws_size,
                              hipStream_t stream)
{
    (void)in_sizes; (void)n_in; (void)out_size; (void)ws_size;
    const float* x  = (const float*)d_in[0];
    const float* Wq = (const float*)d_in[1];
    const float* Wk = (const float*)d_in[2];
    const float* Wv = (const float*)d_in[3];
    const float* Wo = (const float*)d_in[4];

    float* y_out = (float*)d_out;            // (B,T,C) f32
    float* k_out = y_out + NELT;             // (B,H,T,Hd) f32
    float* v_out = k_out + NELT;             // (B,H,T,Hd) f32

    short* S0 = (short*)d_ws;                // xb -> yab
    short* S1 = S0 + NELT;                   // Wqkv bf16 -> kb
    short* S2 = S1 + NELT;                   // qb -> wob
    short* S3 = S2 + NELT;                   // vb

    convert_all<<<dim3((N4X + 3 * N4W) / 256), 256, 0, stream>>>(x, Wq, Wk, Wv, S0, S1);
    gemm_qkv<<<dim3(MM/128, CC/128, 3), 256, 0, stream>>>(S0, S1, S2, k_out, v_out, S3);
    rope_qknorm<<<dim3((BB*HH*TT)/4), 256, 0, stream>>>(S2, k_out, S1);
    attn_mfma<<<dim3(TT/64, BB*HH), 256, 0, stream>>>(S2, S1, S3, S0);
    convert_wo<<<dim3(N4W / 256), 256, 0, stream>>>(Wo, S2);
    gemm_out<<<dim3(MM/128, CC/128), 256, 0, stream>>>(S0, S2, y_out);
}

// Round 6
// 290.084 us; speedup vs baseline: 1.5377x; 1.5377x over previous
//
#include <hip/hip_runtime.h>
#include <hip/hip_bf16.h>
#include <math.h>

// Problem constants
#define BB 8
#define TT 1024
#define CC 768
#define HH 12
#define HD 64
#define MM (BB*TT)           // 8192 rows
#define NELT (MM*CC)         // 6291456 elements per tensor
#define WELT (CC*CC)         // 589824 elements per weight

typedef short bf16x8 __attribute__((ext_vector_type(8)));   // 8 bf16 = 4 VGPR
typedef float f32x4  __attribute__((ext_vector_type(4)));   // MFMA accum

__device__ __forceinline__ short f2bf(float f) {
    union { float f; unsigned u; } a; a.f = f;
    unsigned r = a.u + 0x7fffu + ((a.u >> 16) & 1u);        // RNE
    return (short)(r >> 16);
}
__device__ __forceinline__ float bf2f(short s) {
    union { unsigned u; float f; } a; a.u = ((unsigned)(unsigned short)s) << 16;
    return a.f;
}

// async global->LDS, 16B per lane. LDS dest = wave-uniform base + lane*16.
__device__ __forceinline__ void g2lds16(const short* g, short* l) {
    __builtin_amdgcn_global_load_lds(
        (const __attribute__((address_space(1))) unsigned int*)g,
        (__attribute__((address_space(3))) unsigned int*)l, 16, 0, 0);
}

// ---------------------------------------------------------------------------
// Convert f32 -> bf16: x (NELT) and Wq/Wk/Wv (3*WELT packed) in one pass.
// ---------------------------------------------------------------------------
#define N4X (NELT/4)         // 1572864
#define N4W (WELT/4)         // 147456
__global__ __launch_bounds__(256)
void convert_all(const float* __restrict__ x,
                 const float* __restrict__ Wq, const float* __restrict__ Wk,
                 const float* __restrict__ Wv,
                 short* __restrict__ xb, short* __restrict__ wb)
{
    const int i = blockIdx.x * 256 + threadIdx.x;   // float4 index
    const float* src; short* dst; int off;
    if (i < N4X) { src = x; dst = xb; off = i; }
    else {
        const int j = i - N4X;
        const int w = j / N4W;  off = j - w * N4W;
        src = (w == 0) ? Wq : (w == 1) ? Wk : Wv;
        dst = wb + w * WELT;
    }
    const float4 v = ((const float4*)src)[off];
    short4 h;
    h.x = f2bf(v.x); h.y = f2bf(v.y); h.z = f2bf(v.z); h.w = f2bf(v.w);
    ((short4*)dst)[off] = h;
}

__global__ __launch_bounds__(256)
void convert_wo(const float* __restrict__ Wo, short* __restrict__ wob)
{
    const int i = blockIdx.x * 256 + threadIdx.x;   // float4 index, N4W total
    const float4 v = ((const float4*)Wo)[i];
    short4 h;
    h.x = f2bf(v.x); h.y = f2bf(v.y); h.z = f2bf(v.z); h.w = f2bf(v.w);
    ((short4*)wob)[i] = h;
}

// ---------------------------------------------------------------------------
// m97-style bf16 MFMA GEMM core: C[128,128] tile of A[M,768] @ W[N,768]^T.
// 256 thr = 4 waves (2x2), wave = 64x64 = 4x4 16x16 frags. BK=64.
// Staging: global_load_lds width-16, LINEAR LDS [128][64] dest; the chunk
// permutation pc = lc ^ (row&7) is applied on the GLOBAL SOURCE address and
// again on the ds_read side (involution) -> conflict-free b128 frag reads.
// Two barriers per K-step (m97 structure). After the loop the LDS buffer is
// free for epilogue scratch (one extra barrier inside).
// ---------------------------------------------------------------------------
__device__ __forceinline__ void gemm_core_dma(const short* __restrict__ A,
                                              const short* __restrict__ W,
                                              short* Sbuf,
                                              int row0, int col0,
                                              f32x4 acc[4][4])
{
    const int tid  = threadIdx.x;
    const int lane = tid & 63, wid = tid >> 6;
    const int wr   = (wid >> 1) * 64, wc = (wid & 1) * 64;
    const int fr   = lane & 15, fg = lane >> 4;
    short* As = Sbuf;              // [128][64]
    short* Bs = Sbuf + 128 * 64;

    // staging decode: 1024 16B chunks per tensor, 4 wave-collective loads
    int srow[4], slc[4];
#pragma unroll
    for (int it = 0; it < 4; ++it) {
        const int ch = it * 256 + wid * 64 + lane;
        srow[it] = ch >> 3;
        slc[it]  = (ch & 7) ^ (srow[it] & 7);    // inverse-swizzled source
    }

    for (int k0 = 0; k0 < 768; k0 += 64) {
        __syncthreads();
#pragma unroll
        for (int it = 0; it < 4; ++it) {
            const int lbase = (it * 256 + wid * 64) * 8;   // wave-uniform
            g2lds16(&A[(size_t)(row0 + srow[it]) * 768 + k0 + slc[it] * 8], &As[lbase]);
            g2lds16(&W[(size_t)(col0 + srow[it]) * 768 + k0 + slc[it] * 8], &Bs[lbase]);
        }
        __syncthreads();
#pragma unroll
        for (int kk = 0; kk < 2; ++kk) {
            bf16x8 a[4], b[4];
#pragma unroll
            for (int m = 0; m < 4; ++m) {
                const int r = wr + m * 16 + fr;
                a[m] = *(const bf16x8*)&As[r * 64 + (((kk << 2) | fg) ^ (r & 7)) * 8];
            }
#pragma unroll
            for (int n = 0; n < 4; ++n) {
                const int r = wc + n * 16 + fr;
                b[n] = *(const bf16x8*)&Bs[r * 64 + (((kk << 2) | fg) ^ (r & 7)) * 8];
            }
#pragma unroll
            for (int m = 0; m < 4; ++m)
#pragma unroll
                for (int n = 0; n < 4; ++n)
                    acc[m][n] = __builtin_amdgcn_mfma_f32_16x16x32_bf16(a[m], b[n], acc[m][n], 0, 0, 0);
        }
    }
    __syncthreads();   // all waves done reading As/Bs -> scratch reusable
}

// Epilogue helper: stage one 16-row x 64-col f32 chunk of this wave's acc
// into per-wave LDS scratch, hand each lane one contiguous 16-element row
// segment (row = lane>>2, cols (lane&3)*16..+15).
__device__ __forceinline__ void stage_chunk(float* base, const f32x4 accm[4],
                                            int fr, int fg, int r, int seg,
                                            float v[16])
{
#pragma unroll
    for (int j = 0; j < 4; ++j)
#pragma unroll
        for (int n = 0; n < 4; ++n)
            base[(fg * 4 + j) * 68 + n * 16 + fr] = accm[n][j];
#pragma unroll
    for (int i = 0; i < 4; ++i) {
        const f32x4 t4 = *(const f32x4*)&base[r * 68 + seg * 16 + i * 4];
        v[i * 4 + 0] = t4[0]; v[i * 4 + 1] = t4[1];
        v[i * 4 + 2] = t4[2]; v[i * 4 + 3] = t4[3];
    }
}

// ---------------------------------------------------------------------------
// QKV projection with FUSED RoPE + QK-RMSNorm in the epilogue.
// z=0 -> q bf16 (roped+normed, x0.125 folded), z=1 -> k f32 (final output!)
// + k bf16 copy, z=2 -> v f32 + v bf16 (no rope).
// Wave's 64 cols = exactly one head; after LDS transpose a lane holds 16
// contiguous hd of one (b,h,t) row; rope partner hd^32 lives in lane^2.
// ---------------------------------------------------------------------------
__global__ __launch_bounds__(256)
void gemm_qkv(const short* __restrict__ xb, const short* __restrict__ wb,
              short* __restrict__ qb, float* __restrict__ kf,
              short* __restrict__ kb, float* __restrict__ vf,
              short* __restrict__ vb)
{
    __shared__ short Sbuf[2 * 128 * 64];    // 32 KB
    const int z = blockIdx.z;
    const short* W = wb + (size_t)z * WELT;
    const int row0 = blockIdx.x * 128, col0 = blockIdx.y * 128;

    f32x4 acc[4][4];
#pragma unroll
    for (int m = 0; m < 4; ++m)
#pragma unroll
        for (int n = 0; n < 4; ++n) acc[m][n] = (f32x4){0.f, 0.f, 0.f, 0.f};

    gemm_core_dma(xb, W, Sbuf, row0, col0, acc);

    const int tid = threadIdx.x, lane = tid & 63, wid = tid >> 6;
    const int fr = lane & 15, fg = lane >> 4;
    const int r = lane >> 2, seg = lane & 3;
    float* base = (float*)Sbuf + wid * (16 * 68);
    const int h = (col0 + (wid & 1) * 64) >> 6;

#pragma unroll
    for (int m = 0; m < 4; ++m) {
        float v[16];
        stage_chunk(base, acc[m], fr, fg, r, seg, v);

        const int grow = row0 + (wid >> 1) * 64 + m * 16 + r;
        const int t = grow & 1023, bi = grow >> 10;
        const size_t off = ((size_t)(((bi * HH + h) << 10) | t)) * HD + seg * 16;

        if (z == 2) {
#pragma unroll
            for (int i = 0; i < 4; ++i) {
                float4 w4; w4.x = v[i*4]; w4.y = v[i*4+1]; w4.z = v[i*4+2]; w4.w = v[i*4+3];
                *(float4*)&vf[off + i * 4] = w4;
            }
            short hs[16];
#pragma unroll
            for (int i = 0; i < 16; ++i) hs[i] = f2bf(v[i]);
            *(int4*)&vb[off]     = *(const int4*)&hs[0];
            *(int4*)&vb[off + 8] = *(const int4*)&hs[8];
        } else {
            // RoPE: partner element (hd^32) is in lane^2
            float pv[16];
#pragma unroll
            for (int i = 0; i < 16; ++i) pv[i] = __shfl_xor(v[i], 2);
            float o[16]; float ss2 = 0.f;
#pragma unroll
            for (int i = 0; i < 16; ++i) {
                const float d = (float)((seg & 1) * 16 + i);
                // 10000^(-d/32) = exp2(-log2(10000)/32 * d)
                const float ang = (float)t * exp2f(d * -0.4152410118609203f);
                float sn, cs;
                __sincosf(ang, &sn, &cs);
                o[i] = (seg < 2) ? (v[i] * cs - pv[i] * sn)
                                 : (pv[i] * sn + v[i] * cs);
                ss2 += o[i] * o[i];
            }
            ss2 += __shfl_xor(ss2, 1);
            ss2 += __shfl_xor(ss2, 2);
            const float sc = rsqrtf(ss2 * (1.f / 64.f) + 1e-6f);
            if (z == 0) {
                short hs[16];
#pragma unroll
                for (int i = 0; i < 16; ++i) hs[i] = f2bf(o[i] * sc * 0.125f);
                *(int4*)&qb[off]     = *(const int4*)&hs[0];
                *(int4*)&qb[off + 8] = *(const int4*)&hs[8];
            } else {
                short hs[16];
#pragma unroll
                for (int i = 0; i < 4; ++i) {
                    float4 w4;
                    w4.x = o[i*4]   * sc; w4.y = o[i*4+1] * sc;
                    w4.z = o[i*4+2] * sc; w4.w = o[i*4+3] * sc;
                    *(float4*)&kf[off + i * 4] = w4;
                }
#pragma unroll
                for (int i = 0; i < 16; ++i) hs[i] = f2bf(o[i] * sc);
                *(int4*)&kb[off]     = *(const int4*)&hs[0];
                *(int4*)&kb[off + 8] = *(const int4*)&hs[8];
            }
        }
    }
}

// Output projection: y = y_att(bf16) @ Wo^T(bf16), f32 out, wide stores.
__global__ __launch_bounds__(256)
void gemm_out(const short* __restrict__ yab, const short* __restrict__ wob,
              float* __restrict__ y)
{
    __shared__ short Sbuf[2 * 128 * 64];
    const int row0 = blockIdx.x * 128, col0 = blockIdx.y * 128;
    f32x4 acc[4][4];
#pragma unroll
    for (int m = 0; m < 4; ++m)
#pragma unroll
        for (int n = 0; n < 4; ++n) acc[m][n] = (f32x4){0.f, 0.f, 0.f, 0.f};

    gemm_core_dma(yab, wob, Sbuf, row0, col0, acc);

    const int tid = threadIdx.x, lane = tid & 63, wid = tid >> 6;
    const int fr = lane & 15, fg = lane >> 4;
    const int r = lane >> 2, seg = lane & 3;
    float* base = (float*)Sbuf + wid * (16 * 68);
    const int gcol = col0 + (wid & 1) * 64 + seg * 16;

#pragma unroll
    for (int m = 0; m < 4; ++m) {
        float v[16];
        stage_chunk(base, acc[m], fr, fg, r, seg, v);
        const int grow = row0 + (wid >> 1) * 64 + m * 16 + r;
#pragma unroll
        for (int i = 0; i < 4; ++i) {
            float4 w4; w4.x = v[i*4]; w4.y = v[i*4+1]; w4.z = v[i*4+2]; w4.w = v[i*4+3];
            *(float4*)&y[(size_t)grow * CC + gcol + i * 4] = w4;
        }
    }
}

// ---------------------------------------------------------------------------
// MFMA flash attention, KVBLK=64 (unchanged from round 5).
// ---------------------------------------------------------------------------
__global__ __launch_bounds__(256)
void attn_mfma(const short* __restrict__ qb, const short* __restrict__ kb,
               const short* __restrict__ vb, short* __restrict__ yab)
{
    __shared__ short Ks[64][68];     // [key][hd]   136B rows -> 2-way free
    __shared__ short Vt[64][68];     // [hd][key]
    __shared__ short Ps[4][16][76];  // per wave [qrow][key] 152B rows

    const int qt   = 15 - blockIdx.x;      // big tiles first
    const int bh   = blockIdx.y;           // 0..95
    const int tid  = threadIdx.x;
    const int lane = tid & 63, wid = tid >> 6;
    const int fr   = lane & 15, fg = lane >> 4;
    const int q0   = qt * 64 + wid * 16;

    const short* qbase = qb + (size_t)(bh << 10) * HD;
    const short* kbase = kb + (size_t)(bh << 10) * HD;
    const short* vbase = vb + (size_t)(bh << 10) * HD;

    // Q fragments (rows q0+fr), pre-scaled by 1/8
    bf16x8 aq[2];
#pragma unroll
    for (int ks = 0; ks < 2; ++ks)
        aq[ks] = *(const bf16x8*)&qbase[(q0 + fr) * HD + ks * 32 + fg * 8];

    f32x4 acc[4];
#pragma unroll
    for (int n = 0; n < 4; ++n) acc[n] = (f32x4){0.f, 0.f, 0.f, 0.f};
    float mrow[4] = {-1e30f, -1e30f, -1e30f, -1e30f};
    float lrow[4] = {0.f, 0.f, 0.f, 0.f};

    // staging decode: 512 16B chunks per tensor, 2 per thread
    int kk_[2], kc_[2], vk_[2], vh_[2];
#pragma unroll
    for (int i = 0; i < 2; ++i) {
        const int p = i * 256 + tid;
        kk_[i] = p >> 3;  kc_[i] = (p & 7) * 8;     // K: key row, hd offset
        vk_[i] = p & 63;  vh_[i] = (p >> 6) * 8;    // V: key, hd block
    }

    int4 kr[2], vr[2];
#pragma unroll
    for (int i = 0; i < 2; ++i) {
        kr[i] = *(const int4*)&kbase[(size_t)kk_[i] * HD + kc_[i]];
        vr[i] = *(const int4*)&vbase[(size_t)vk_[i] * HD + vh_[i]];
    }

    const int ktend = qt + 1;
    for (int kt = 0; kt < ktend; ++kt) {
        __syncthreads();                       // prev tile's readers done
#pragma unroll
        for (int i = 0; i < 2; ++i) {
            *(int4*)&Ks[kk_[i]][kc_[i]] = kr[i];
            const short* vp = (const short*)&vr[i];
#pragma unroll
            for (int j = 0; j < 8; ++j) Vt[vh_[i] + j][vk_[i]] = vp[j];
        }
        if (kt + 1 < ktend) {                  // prefetch next tile (overlaps compute)
#pragma unroll
            for (int i = 0; i < 2; ++i) {
                kr[i] = *(const int4*)&kbase[(size_t)((kt + 1) * 64 + kk_[i]) * HD + kc_[i]];
                vr[i] = *(const int4*)&vbase[(size_t)((kt + 1) * 64 + vk_[i]) * HD + vh_[i]];
            }
        }
        __syncthreads();                       // tile staged

        // S = Q K^T : rows = q (fg*4+j), cols = key (ns*16+fr)
        f32x4 s[4];
#pragma unroll
        for (int ns = 0; ns < 4; ++ns) {
            const bf16x8 bk0 = *(const bf16x8*)&Ks[ns * 16 + fr][fg * 8];
            const bf16x8 bk1 = *(const bf16x8*)&Ks[ns * 16 + fr][32 + fg * 8];
            f32x4 z = (f32x4){0.f, 0.f, 0.f, 0.f};
            z = __builtin_amdgcn_mfma_f32_16x16x32_bf16(aq[0], bk0, z, 0, 0, 0);
            z = __builtin_amdgcn_mfma_f32_16x16x32_bf16(aq[1], bk1, z, 0, 0, 0);
            s[ns] = z;
        }

        const bool diag = (kt == qt);          // only the diagonal tile masks
#pragma unroll
        for (int j = 0; j < 4; ++j) {
            const int q = q0 + fg * 4 + j;
            float sv[4];
#pragma unroll
            for (int ns = 0; ns < 4; ++ns) {
                const int kc = kt * 64 + ns * 16 + fr;
                sv[ns] = (!diag || kc <= q) ? s[ns][j] : -1e30f;
            }
            float cm = fmaxf(fmaxf(sv[0], sv[1]), fmaxf(sv[2], sv[3]));
            cm = fmaxf(cm, __shfl_xor(cm, 1));
            cm = fmaxf(cm, __shfl_xor(cm, 2));
            cm = fmaxf(cm, __shfl_xor(cm, 4));
            cm = fmaxf(cm, __shfl_xor(cm, 8));
            const float mnew = fmaxf(mrow[j], cm);
            const float f = __expf(mrow[j] - mnew);
            float rs = 0.f;
#pragma unroll
            for (int ns = 0; ns < 4; ++ns) {
                const float p = __expf(sv[ns] - mnew);
                rs += p;
                Ps[wid][fg * 4 + j][ns * 16 + fr] = f2bf(p);
            }
            rs += __shfl_xor(rs, 1);
            rs += __shfl_xor(rs, 2);
            rs += __shfl_xor(rs, 4);
            rs += __shfl_xor(rs, 8);
            lrow[j] = lrow[j] * f + rs;
            mrow[j] = mnew;
            acc[0][j] *= f; acc[1][j] *= f; acc[2][j] *= f; acc[3][j] *= f;
        }

        // O += P V  (Ps per-wave: in-wave lgkmcnt ordering, no barrier needed)
#pragma unroll
        for (int ks = 0; ks < 2; ++ks) {
            const bf16x8 pa = *(const bf16x8*)&Ps[wid][fr][ks * 32 + fg * 8];
#pragma unroll
            for (int n = 0; n < 4; ++n) {
                const bf16x8 vfr = *(const bf16x8*)&Vt[n * 16 + fr][ks * 32 + fg * 8];
                acc[n] = __builtin_amdgcn_mfma_f32_16x16x32_bf16(pa, vfr, acc[n], 0, 0, 0);
            }
        }
    }

    // epilogue: y_att (B,T,C) bf16
    const int b = bh / HH, h = bh % HH;
#pragma unroll
    for (int j = 0; j < 4; ++j) {
        const int q = q0 + fg * 4 + j;
        const float inv = 1.f / lrow[j];
#pragma unroll
        for (int n = 0; n < 4; ++n)
            yab[(size_t)(b * TT + q) * CC + h * HD + n * 16 + fr] =
                f2bf(acc[n][j] * inv);
    }
}

// ---------------------------------------------------------------------------
// Memory plan:
//   d_out: y (25.2MB, also hosts kb bf16 as scratch until gemm_out), k, v.
//   d_ws (41.3MB used): S0 xb -> yab | S1 Wqkv bf16 -> wob | S2 qb | S3 vb
// ---------------------------------------------------------------------------
extern "C" void kernel_launch(void* const* d_in, const int* in_sizes, int n_in,
                              void* d_out, int out_size, void* d_ws, size_t ws_size,
                              hipStream_t stream)
{
    (void)in_sizes; (void)n_in; (void)out_size; (void)ws_size;
    const float* x  = (const float*)d_in[0];
    const float* Wq = (const float*)d_in[1];
    const float* Wk = (const float*)d_in[2];
    const float* Wv = (const float*)d_in[3];
    const float* Wo = (const float*)d_in[4];

    float* y_out = (float*)d_out;            // (B,T,C) f32
    float* k_out = y_out + NELT;             // (B,H,T,Hd) f32
    float* v_out = k_out + NELT;             // (B,H,T,Hd) f32
    short* kbb   = (short*)y_out;            // bf16 k scratch in y region
                                             // (dead before gemm_out writes y)

    short* S0 = (short*)d_ws;                // xb -> yab
    short* S1 = S0 + NELT;                   // Wq/Wk/Wv bf16 -> wob
    short* S2 = S1 + 3 * WELT;               // qb
    short* S3 = S2 + NELT;                   // vb

    convert_all<<<dim3((N4X + 3 * N4W) / 256), 256, 0, stream>>>(x, Wq, Wk, Wv, S0, S1);
    gemm_qkv<<<dim3(MM/128, CC/128, 3), 256, 0, stream>>>(S0, S1, S2, k_out, kbb, v_out, S3);
    attn_mfma<<<dim3(TT/64, BB*HH), 256, 0, stream>>>(S2, kbb, S3, S0);
    convert_wo<<<dim3(N4W / 256), 256, 0, stream>>>(Wo, S1);
    gemm_out<<<dim3(MM/128, CC/128), 256, 0, stream>>>(S0, S1, y_out);
}